// Round 9
// baseline (435.660 us; speedup 1.0000x reference)
//
#include <hip/hip_runtime.h>
#include <stdint.h>

// ---------- types ----------
typedef __attribute__((ext_vector_type(8))) short short8;
typedef __attribute__((ext_vector_type(4))) float floatx4;
typedef __attribute__((ext_vector_type(4))) unsigned short ushort4v;

__device__ inline float bf2f(unsigned short u) {
  union { unsigned int i; float f; } v; v.i = ((unsigned int)u) << 16; return v.f;
}
__device__ inline unsigned short f2bf(float f) {
  union { float f; unsigned int i; } v; v.f = f;
  unsigned int r = v.i + 0x7FFFu + ((v.i >> 16) & 1u);  // round-nearest-even
  return (unsigned short)(r >> 16);
}

// ---------- prep: both layers' weights -> bf16 MFMA-swizzled; zero cnt.
// Wb layout per matrix m: Wb[m][ ((kc*4+q)*4+nt)*16+lc ][j], k=kc*32+q*8+j, c=nt*16+lc
__global__ void conv_prep(const float* __restrict__ W1, const float* __restrict__ root1,
                          const float* __restrict__ W2, const float* __restrict__ root2,
                          unsigned short* __restrict__ Wb, int* __restrict__ cnt, int n2)
{
  int i = blockIdx.x * blockDim.x + threadIdx.x;
  if (i < 2 * 9 * 4096) {
    int layer = i / 36864;
    int rem = i - layer * 36864;
    int m = rem >> 12, rem2 = rem & 4095, k = rem2 >> 6, c = rem2 & 63;
    const float* Wm = layer ? W2 : W1;
    const float* rt = layer ? root2 : root1;
    float w = (m < 8) ? Wm[(size_t)m * 4096 + k * 64 + c] : rt[(size_t)k * 64 + c];
    int kc = k >> 5, q = (k >> 3) & 3, j = k & 7, nt = c >> 4, lcv = c & 15;
    Wb[(size_t)(layer * 9 + m) * 4096 + (size_t)(((kc * 4 + q) * 4 + nt) * 16 + lcv) * 8 + j] = f2bf(w);
  } else {
    int z = i - 2 * 9 * 4096;
    if (z < n2) cnt[z] = 0;
  }
}

// ---------- shared transform tile: out Y[n][g*64+c] (8 groups, bf16) and
// accR[n][c] = root-term + bias (fp32). Input is fp32 rows (optional relu).
// B-frags direct from swizzled Wb (same addr across waves -> L1-hot). No LDS.
__device__ __forceinline__ void transform_tile(
    int t, int N, int lane, const float* __restrict__ X, int relu,
    const unsigned short* __restrict__ Wb, const float* __restrict__ bias,
    unsigned short* __restrict__ Y, float* __restrict__ accR)
{
  const int lc = lane & 15, quad = lane >> 4;
  const int nb = t << 4;
  const int row = min(nb + lc, N - 1);
  const float* xr = X + (size_t)row * 64;
  short8 a0, a1;
#pragma unroll
  for (int j = 0; j < 8; ++j) {
    float v0 = xr[quad * 8 + j];
    float v1 = xr[32 + quad * 8 + j];
    if (relu) { v0 = fmaxf(v0, 0.f); v1 = fmaxf(v1, 0.f); }
    a0[j] = (short)f2bf(v0);
    a1[j] = (short)f2bf(v1);
  }
#pragma unroll
  for (int g = 0; g < 9; ++g) {
#pragma unroll
    for (int nt = 0; nt < 4; ++nt) {
      const short8 b0 = *(const short8*)&Wb[(size_t)g * 4096 +
          (size_t)(((0 * 4 + quad) * 4 + nt) * 16 + lc) * 8];
      const short8 b1 = *(const short8*)&Wb[(size_t)g * 4096 +
          (size_t)(((1 * 4 + quad) * 4 + nt) * 16 + lc) * 8];
      floatx4 d = {0.f, 0.f, 0.f, 0.f};
      d = __builtin_amdgcn_mfma_f32_16x16x32_bf16(a0, b0, d, 0, 0, 0);
      d = __builtin_amdgcn_mfma_f32_16x16x32_bf16(a1, b1, d, 0, 0, 0);
      const int c = nt * 16 + lc;
      if (g < 8) {
#pragma unroll
        for (int i = 0; i < 4; ++i) {
          int r_ = nb + quad * 4 + i;
          if (r_ < N) Y[(size_t)r_ * 512 + g * 64 + c] = f2bf(d[i]);
        }
      } else {
        const float bv = bias[c];
#pragma unroll
        for (int i = 0; i < 4; ++i) {
          int r_ = nb + quad * 4 + i;
          if (r_ < N) accR[(size_t)r_ * 64 + c] = d[i] + bv;
        }
      }
    }
  }
}

// ---------- FUSED: CSR count pass || layer-1 transform. 1:1 interleave.
// Count role: 4 edges/thread (int4 loads, 4 independent atomics in flight,
// ushort4 rank store) -> 4x fewer count blocks, no wave-slot hogging while
// the atomic returns are in flight; transform blocks get the occupancy.
__global__ void __launch_bounds__(256)
count_and_t1(const int* __restrict__ dst, const int* __restrict__ et,
             int* __restrict__ cnt, unsigned short* __restrict__ rank, int E,
             const float* __restrict__ x, const unsigned short* __restrict__ Wb1,
             const float* __restrict__ b1, unsigned short* __restrict__ Y,
             float* __restrict__ accA, int N, int TB)
{
  const int bx = (int)blockIdx.x;
  const bool isT = ((bx & 1) == 0) && ((bx >> 1) < TB);
  if (isT) {
    const int lane = threadIdx.x & 63;
    const int wave = threadIdx.x >> 6;
    const int t = (bx >> 1) * 4 + wave;
    if (t < ((N + 15) >> 4))
      transform_tile(t, N, lane, x, 0, Wb1, b1, Y, accA);
  } else {
    const int nT = min((bx + 1) >> 1, TB);     // transform blocks before bx
    const int cb = bx - nT;                    // bijective count-block index
    const int e0 = cb * 1024 + (int)threadIdx.x * 4;
    if (e0 + 3 < E) {
      const int4 d4 = *(const int4*)&dst[e0];
      const int4 t4 = *(const int4*)&et[e0];
      unsigned short r0 = (unsigned short)atomicAdd(&cnt[d4.x * 8 + t4.x], 1);
      unsigned short r1 = (unsigned short)atomicAdd(&cnt[d4.y * 8 + t4.y], 1);
      unsigned short r2 = (unsigned short)atomicAdd(&cnt[d4.z * 8 + t4.z], 1);
      unsigned short r3 = (unsigned short)atomicAdd(&cnt[d4.w * 8 + t4.w], 1);
      ushort4v rr = { r0, r1, r2, r3 };
      *(ushort4v*)&rank[e0] = rr;
    } else {
      for (int k = 0; k < 4; ++k) {
        int e = e0 + k;
        if (e < E) rank[e] = (unsigned short)atomicAdd(&cnt[dst[e] * 8 + et[e]], 1);
      }
    }
  }
}

// ---------- layer-2 transform (standalone): relu(accA) -> Y, accB ----------
__global__ void __launch_bounds__(256)
transform_l2(const float* __restrict__ accA, const unsigned short* __restrict__ Wb2,
             const float* __restrict__ b2, unsigned short* __restrict__ Y,
             float* __restrict__ accB, int N)
{
  const int lane = threadIdx.x & 63;
  const int wave = threadIdx.x >> 6;
  const int t = blockIdx.x * 4 + wave;
  if (t < ((N + 15) >> 4))
    transform_tile(t, N, lane, accA, 1, Wb2, b2, Y, accB);
}

// ---------- exclusive scan of cnt[n2] -> eptr8[n2] (+eptr8[n2]=E) ----------
#define SCAN_T 256
#define SCAN_E 4   // 1024 elems per block

__global__ void scan1(const int* __restrict__ cnt, int* __restrict__ bsum, int n) {
  __shared__ int lds[SCAN_T];
  int base = blockIdx.x * (SCAN_T * SCAN_E);
  int tid = threadIdx.x;
  int s = 0;
#pragma unroll
  for (int j = 0; j < SCAN_E; ++j) {
    int i = base + tid * SCAN_E + j;
    if (i < n) s += cnt[i];
  }
  lds[tid] = s; __syncthreads();
  for (int off = SCAN_T / 2; off > 0; off >>= 1) {
    if (tid < off) lds[tid] += lds[tid + off];
    __syncthreads();
  }
  if (tid == 0) bsum[blockIdx.x] = lds[0];
}

__global__ void scan2(int* __restrict__ bsum, int* __restrict__ eptr, int nb, int n) {
  __shared__ int lds[SCAN_T];
  int tid = threadIdx.x;
  int loc[4]; int s = 0;
#pragma unroll
  for (int j = 0; j < 4; ++j) {
    int i = tid * 4 + j;
    loc[j] = (i < nb) ? bsum[i] : 0; s += loc[j];
  }
  lds[tid] = s; __syncthreads();
  for (int off = 1; off < SCAN_T; off <<= 1) {   // Hillis-Steele inclusive
    int v = (tid >= off) ? lds[tid - off] : 0;
    __syncthreads();
    lds[tid] += v;
    __syncthreads();
  }
  int run = (tid > 0 ? lds[tid - 1] : 0);
#pragma unroll
  for (int j = 0; j < 4; ++j) {
    int i = tid * 4 + j;
    if (i < nb) { int v = loc[j]; bsum[i] = run; run += v; }
  }
  if (tid == 0) eptr[n] = lds[SCAN_T - 1];   // total = E
}

__global__ void scan3(const int* __restrict__ cnt, const int* __restrict__ bsum,
                      int* __restrict__ eptr, int n) {
  __shared__ int lds[SCAN_T];
  int base = blockIdx.x * (SCAN_T * SCAN_E);
  int tid = threadIdx.x;
  int loc[SCAN_E]; int s = 0;
#pragma unroll
  for (int j = 0; j < SCAN_E; ++j) {
    int i = base + tid * SCAN_E + j;
    loc[j] = (i < n) ? cnt[i] : 0; s += loc[j];
  }
  lds[tid] = s; __syncthreads();
  for (int off = 1; off < SCAN_T; off <<= 1) {
    int v = (tid >= off) ? lds[tid - off] : 0;
    __syncthreads();
    lds[tid] += v;
    __syncthreads();
  }
  int run = (tid > 0 ? lds[tid - 1] : 0) + bsum[blockIdx.x];
#pragma unroll
  for (int j = 0; j < SCAN_E; ++j) {
    int i = base + tid * SCAN_E + j;
    if (i < n) { eptr[i] = run; run += loc[j]; }
  }
}

// ---- CSR pass 2: deterministic placement, NO atomics. entry = (src<<3)|rel ----
__global__ void scatter_edges(const int* __restrict__ src, const int* __restrict__ dst,
                              const int* __restrict__ et, const int* __restrict__ eptr8,
                              const unsigned short* __restrict__ rank,
                              unsigned* __restrict__ entry, int E) {
  int e = blockIdx.x * blockDim.x + threadIdx.x;
  if (e < E) {
    int d = dst[e], r = et[e];
    int p = eptr8[d * 8 + r] + (int)rank[e];
    entry[p] = ((unsigned)src[e] << 3) | (unsigned)r;
  }
}

// ---------- CSR edge aggregation: one wave per dst node, no atomics.
// acc[d][lane] += sum_e Y[src_e][rel_e*64+lane] / cnt(d,rel_e).
// Paired-dword gather: lanes 0-31 carry the EVEN edge of each pair (features
// 2*sub, 2*sub+1 as one dword), lanes 32-63 the ODD edge -> one load
// instruction covers TWO edge rows => 16 edges in flight at vmcnt depth 8.
// Edge records prefetched 64-at-a-time (coalesced) + __shfl broadcast.
// Final 4-shfl repack restores feature-per-lane before the acc write.
__global__ void __launch_bounds__(256)
edge_agg_csr(const unsigned short* __restrict__ Y, const int* __restrict__ eptr8,
             const unsigned* __restrict__ entry, float* __restrict__ acc, int N)
{
  const int wid  = (blockIdx.x * blockDim.x + threadIdx.x) >> 6;
  const int lane = threadIdx.x & 63;
  if (wid >= N) return;
  const int bv = eptr8[wid * 8 + (lane < 9 ? lane : 8)];
  const int lo = __shfl(bv, 0), hi = __shfl(bv, 8);
  const int wdt = __shfl(bv, (lane & 7) + 1) - __shfl(bv, lane & 7);
  const float invv = 1.0f / (float)max(wdt, 1);   // lane r (0..7): 1/cnt(rel r)

  const int half = lane >> 5;      // 0 = even-edge stream, 1 = odd-edge stream
  const int sub  = lane & 31;      // feature pair: features 2*sub, 2*sub+1
  float s0 = 0.f, s1 = 0.f;

#define GATHER2(ename, vname, wname, pidx)                                     \
  unsigned ename = __shfl(en, 2 * (pidx) + half);                              \
  unsigned vname = *(const unsigned*)&Y[(size_t)(ename >> 3) * 512 +           \
                                        (ename & 7) * 64 + sub * 2];           \
  float wname = __shfl(invv, (int)(ename & 7));

  for (int base = lo; base < hi; base += 64) {
    const int rem = hi - base;
    const int mm = rem < 64 ? rem : 64;
    const unsigned en = entry[base + (lane < mm ? lane : mm - 1)];
    const int pairs = mm >> 1;
    int i = 0;
    for (; i + 8 <= pairs; i += 8) {
      GATHER2(ea, va, wa, i)     GATHER2(eb, vb, wb, i + 1)
      GATHER2(ec, vc, wc, i + 2) GATHER2(ed, vd, wd, i + 3)
      GATHER2(ee, ve, we, i + 4) GATHER2(ef, vf, wf, i + 5)
      GATHER2(eg, vg, wg, i + 6) GATHER2(eh, vh, wh, i + 7)
      s0 += bf2f((unsigned short)(va & 0xffff)) * wa + bf2f((unsigned short)(vb & 0xffff)) * wb
          + bf2f((unsigned short)(vc & 0xffff)) * wc + bf2f((unsigned short)(vd & 0xffff)) * wd
          + bf2f((unsigned short)(ve & 0xffff)) * we + bf2f((unsigned short)(vf & 0xffff)) * wf
          + bf2f((unsigned short)(vg & 0xffff)) * wg + bf2f((unsigned short)(vh & 0xffff)) * wh;
      s1 += bf2f((unsigned short)(va >> 16)) * wa + bf2f((unsigned short)(vb >> 16)) * wb
          + bf2f((unsigned short)(vc >> 16)) * wc + bf2f((unsigned short)(vd >> 16)) * wd
          + bf2f((unsigned short)(ve >> 16)) * we + bf2f((unsigned short)(vf >> 16)) * wf
          + bf2f((unsigned short)(vg >> 16)) * wg + bf2f((unsigned short)(vh >> 16)) * wh;
    }
    for (; i < pairs; ++i) {
      GATHER2(ea, va, wa, i)
      s0 += bf2f((unsigned short)(va & 0xffff)) * wa;
      s1 += bf2f((unsigned short)(va >> 16)) * wa;
    }
    if (mm & 1) {   // leftover odd edge -> even-stream lanes only
      unsigned e0 = __shfl(en, mm - 1);
      float w0 = __shfl(invv, (int)(e0 & 7));
      if (lane < 32) {
        unsigned v = *(const unsigned*)&Y[(size_t)(e0 >> 3) * 512 + (e0 & 7) * 64 + sub * 2];
        s0 += bf2f((unsigned short)(v & 0xffff)) * w0;
        s1 += bf2f((unsigned short)(v >> 16)) * w0;
      }
    }
  }
#undef GATHER2
  // repack: feature f = even-stream[lane f>>1, comp f&1] + odd-stream[lane 32+(f>>1), comp f&1]
  float a0 = __shfl(s0, lane >> 1);
  float a1 = __shfl(s1, lane >> 1);
  float b0 = __shfl(s0, 32 + (lane >> 1));
  float b1 = __shfl(s1, 32 + (lane >> 1));
  float sum = ((lane & 1) ? a1 : a0) + ((lane & 1) ? b1 : b0);
  acc[(size_t)wid * 64 + lane] += sum;
}

// lower_bound over sorted batch
__device__ inline int lbound(const int* __restrict__ batch, int Nn, int g) {
  int lo = 0, hi = Nn;
  while (lo < hi) { int m = (lo + hi) >> 1; if (batch[m] < g) lo = m + 1; else hi = m; }
  return lo;
}

// ---------- mean pool, two-stage (bounds via inline binary search) ----------
#define PS 24
__global__ void __launch_bounds__(256)
pool1(const float* __restrict__ acc, const int* __restrict__ batch,
      float* __restrict__ partial, int N, int G)
{
  const int g = blockIdx.x;
  const int s = blockIdx.y;
  const int lane = threadIdx.x & 63;
  const int w = threadIdx.x >> 6;
  const int lo = lbound(batch, N, g);
  const int hi = lbound(batch, N, g + 1);
  const int len = hi - lo;
  const int a = lo + (int)(((long long)len * s) / PS);
  const int b = lo + (int)(((long long)len * (s + 1)) / PS);
  float sum = 0.f;
  for (int n = a + w; n < b; n += 4) sum += acc[(size_t)n * 64 + lane];
  __shared__ float red[4][64];
  red[w][lane] = sum;
  __syncthreads();
  if (w == 0)
    partial[((size_t)g * PS + s) * 64 + lane] =
        red[0][lane] + red[1][lane] + red[2][lane] + red[3][lane];
}

__global__ void pool2(const float* __restrict__ partial, const int* __restrict__ batch,
                      float* __restrict__ out, int N, int G)
{
  const int g = blockIdx.x;
  const int lane = threadIdx.x;   // 64 threads
  float t = 0.f;
#pragma unroll
  for (int s = 0; s < PS; ++s) t += partial[((size_t)g * PS + s) * 64 + lane];
  const int len = lbound(batch, N, g + 1) - lbound(batch, N, g);
  out[(size_t)g * 64 + lane] = t / fmaxf((float)len, 1.0f);
}

// ---------- launch ----------
extern "C" void kernel_launch(void* const* d_in, const int* in_sizes, int n_in,
                              void* d_out, int out_size, void* d_ws, size_t ws_size,
                              hipStream_t stream)
{
  const float* x     = (const float*)d_in[0];
  const int*   ei    = (const int*)d_in[1];
  const int*   etype = (const int*)d_in[2];
  const int*   batch = (const int*)d_in[3];
  const float* W1    = (const float*)d_in[4];
  const float* root1 = (const float*)d_in[5];
  const float* b1    = (const float*)d_in[6];
  const float* W2    = (const float*)d_in[7];
  const float* root2 = (const float*)d_in[8];
  const float* b2    = (const float*)d_in[9];

  const int N = in_sizes[0] / 64;
  const int E = in_sizes[1] / 2;
  const int R = in_sizes[4] / (64 * 64);   // == 8
  const int G = out_size / 64;
  const int* srcp = ei;
  const int* dstp = ei + E;
  const int n2 = N * R;   // (dst,rel) bins

  // workspace carve-up (256B aligned), ~164 MB
  char* ws = (char*)d_ws;
  size_t off = 0;
  auto carve = [&](size_t bytes) -> void* {
    void* p = ws + off; off = (off + bytes + 255) & ~(size_t)255; return p;
  };
  float*          accA    = (float*)carve((size_t)N * 64 * 4);
  float*          accB    = (float*)carve((size_t)N * 64 * 4);
  unsigned short* Y       = (unsigned short*)carve((size_t)N * R * 64 * 2);
  int*            eptr8   = (int*)carve((size_t)(n2 + 1) * 4);
  unsigned*       entry   = (unsigned*)carve((size_t)E * 4);
  int*            bsum    = (int*)carve(1024 * 4);
  float*          partial = (float*)carve((size_t)G * PS * 64 * 4);
  unsigned short* Wb      = (unsigned short*)carve((size_t)2 * 9 * 4096 * 2);
  // dead-before-first-write aliases into accB (first written by transform_l2,
  // which runs AFTER scan3(cnt) and scatter(rank); same stream => ordered).
  // NOTE: must NOT alias accA — it is written concurrently by the fused kernel.
  int*            cnt  = (int*)accB;                               // 3.2 MB
  unsigned short* rank = (unsigned short*)((char*)accB + ((size_t)4 << 20));
  (void)ws_size; (void)n_in;

  const int nb2 = (n2 + SCAN_T * SCAN_E - 1) / (SCAN_T * SCAN_E);
  const int tiles = (N + 15) >> 4;
  const int TB = (tiles + 3) / 4;            // transform blocks (wave per tile)
  const int CB = (E + 1023) / 1024;          // count blocks (4 edges/thread)
  const int prep_total = 2 * 9 * 4096 + n2;

  // ---- prep: weights -> swizzled bf16, zero cnt ----
  conv_prep<<<(prep_total + 255) / 256, 256, 0, stream>>>(W1, root1, W2, root2, Wb, cnt, n2);

  // ---- FUSED: CSR count (atomic-bound) || layer-1 transform (MFMA/write-bound) ----
  count_and_t1<<<CB + TB, 256, 0, stream>>>(dstp, etype, cnt, rank, E,
                                            x, Wb, b1, Y, accA, N, TB);

  // ---- CSR finish ----
  scan1<<<nb2, SCAN_T, 0, stream>>>(cnt, bsum, n2);
  scan2<<<1, SCAN_T, 0, stream>>>(bsum, eptr8, nb2, n2);
  scan3<<<nb2, SCAN_T, 0, stream>>>(cnt, bsum, eptr8, n2);
  scatter_edges<<<(E + 255) / 256, 256, 0, stream>>>(srcp, dstp, etype, eptr8, rank, entry, E);

  const int aggBlocks = (N * 64 + 255) / 256;

  // ---- layer 1 aggregate ----
  edge_agg_csr<<<aggBlocks, 256, 0, stream>>>(Y, eptr8, entry, accA, N);

  // ---- layer 2 ----
  transform_l2<<<TB, 256, 0, stream>>>(accA, Wb + 9 * 4096, b2, Y, accB, N);
  edge_agg_csr<<<aggBlocks, 256, 0, stream>>>(Y, eptr8, entry, accB, N);

  // ---- global mean pool ----
  dim3 pgrid(G, PS);
  pool1<<<pgrid, 256, 0, stream>>>(accB, batch, partial, N, G);
  pool2<<<G, 64, 0, stream>>>(partial, batch, (float*)d_out, N, G);
}

// Round 11
// 399.421 us; speedup vs baseline: 1.0907x; 1.0907x over previous
//
#include <hip/hip_runtime.h>
#include <stdint.h>

// ---------- types ----------
typedef __attribute__((ext_vector_type(8))) short short8;
typedef __attribute__((ext_vector_type(4))) float floatx4;
typedef __attribute__((ext_vector_type(4))) unsigned short ushort4v;

__device__ inline float bf2f(unsigned short u) {
  union { unsigned int i; float f; } v; v.i = ((unsigned int)u) << 16; return v.f;
}
__device__ inline unsigned short f2bf(float f) {
  union { float f; unsigned int i; } v; v.f = f;
  unsigned int r = v.i + 0x7FFFu + ((v.i >> 16) & 1u);  // round-nearest-even
  return (unsigned short)(r >> 16);
}

// ---------- prep: both layers' weights -> bf16 MFMA-swizzled; zero cnt.
// Wb layout per matrix m: Wb[m][ ((kc*4+q)*4+nt)*16+lc ][j], k=kc*32+q*8+j, c=nt*16+lc
__global__ void conv_prep(const float* __restrict__ W1, const float* __restrict__ root1,
                          const float* __restrict__ W2, const float* __restrict__ root2,
                          unsigned short* __restrict__ Wb, int* __restrict__ cnt, int n2)
{
  int i = blockIdx.x * blockDim.x + threadIdx.x;
  if (i < 2 * 9 * 4096) {
    int layer = i / 36864;
    int rem = i - layer * 36864;
    int m = rem >> 12, rem2 = rem & 4095, k = rem2 >> 6, c = rem2 & 63;
    const float* Wm = layer ? W2 : W1;
    const float* rt = layer ? root2 : root1;
    float w = (m < 8) ? Wm[(size_t)m * 4096 + k * 64 + c] : rt[(size_t)k * 64 + c];
    int kc = k >> 5, q = (k >> 3) & 3, j = k & 7, nt = c >> 4, lcv = c & 15;
    Wb[(size_t)(layer * 9 + m) * 4096 + (size_t)(((kc * 4 + q) * 4 + nt) * 16 + lcv) * 8 + j] = f2bf(w);
  } else {
    int z = i - 2 * 9 * 4096;
    if (z < n2) cnt[z] = 0;
  }
}

// ---------- shared transform tile: out Y[n][g*64+c] (8 groups, bf16) and
// accR[n][c] = root-term + bias (fp32). Input is fp32 rows (optional relu).
// B-frags direct from swizzled Wb (same addr across waves -> L1-hot). No LDS.
__device__ __forceinline__ void transform_tile(
    int t, int N, int lane, const float* __restrict__ X, int relu,
    const unsigned short* __restrict__ Wb, const float* __restrict__ bias,
    unsigned short* __restrict__ Y, float* __restrict__ accR)
{
  const int lc = lane & 15, quad = lane >> 4;
  const int nb = t << 4;
  const int row = min(nb + lc, N - 1);
  const float* xr = X + (size_t)row * 64;
  short8 a0, a1;
#pragma unroll
  for (int j = 0; j < 8; ++j) {
    float v0 = xr[quad * 8 + j];
    float v1 = xr[32 + quad * 8 + j];
    if (relu) { v0 = fmaxf(v0, 0.f); v1 = fmaxf(v1, 0.f); }
    a0[j] = (short)f2bf(v0);
    a1[j] = (short)f2bf(v1);
  }
#pragma unroll
  for (int g = 0; g < 9; ++g) {
#pragma unroll
    for (int nt = 0; nt < 4; ++nt) {
      const short8 b0 = *(const short8*)&Wb[(size_t)g * 4096 +
          (size_t)(((0 * 4 + quad) * 4 + nt) * 16 + lc) * 8];
      const short8 b1 = *(const short8*)&Wb[(size_t)g * 4096 +
          (size_t)(((1 * 4 + quad) * 4 + nt) * 16 + lc) * 8];
      floatx4 d = {0.f, 0.f, 0.f, 0.f};
      d = __builtin_amdgcn_mfma_f32_16x16x32_bf16(a0, b0, d, 0, 0, 0);
      d = __builtin_amdgcn_mfma_f32_16x16x32_bf16(a1, b1, d, 0, 0, 0);
      const int c = nt * 16 + lc;
      if (g < 8) {
#pragma unroll
        for (int i = 0; i < 4; ++i) {
          int r_ = nb + quad * 4 + i;
          if (r_ < N) Y[(size_t)r_ * 512 + g * 64 + c] = f2bf(d[i]);
        }
      } else {
        const float bv = bias[c];
#pragma unroll
        for (int i = 0; i < 4; ++i) {
          int r_ = nb + quad * 4 + i;
          if (r_ < N) accR[(size_t)r_ * 64 + c] = d[i] + bv;
        }
      }
    }
  }
}

// ---------- FUSED: CSR count pass || layer-1 transform. Independent work,
// interleaved 4:1 (count blocks : transform blocks) — round-8 measured config.
__global__ void __launch_bounds__(256)
count_and_t1(const int* __restrict__ dst, const int* __restrict__ et,
             int* __restrict__ cnt, unsigned short* __restrict__ rank, int E,
             const float* __restrict__ x, const unsigned short* __restrict__ Wb1,
             const float* __restrict__ b1, unsigned short* __restrict__ Y,
             float* __restrict__ accA, int N, int TB)
{
  const unsigned bx = blockIdx.x;
  const bool isT = (bx % 5u == 0u) && (bx / 5u < (unsigned)TB);
  if (isT) {
    const int lane = threadIdx.x & 63;
    const int wave = threadIdx.x >> 6;
    const int t = (int)(bx / 5u) * 4 + wave;
    if (t < ((N + 15) >> 4))
      transform_tile(t, N, lane, x, 0, Wb1, b1, Y, accA);
  } else {
    // bijective map to count-block index: subtract # transform blocks before bx
    const unsigned nT = min((bx + 4u) / 5u, (unsigned)TB);
    const int e = (int)(bx - nT) * 256 + (int)threadIdx.x;
    if (e < E) {
      int idx = dst[e] * 8 + et[e];
      rank[e] = (unsigned short)atomicAdd(&cnt[idx], 1);  // rank within (dst,rel) bin
    }
  }
}

// ---------- layer-2 transform (standalone): relu(accA) -> Y, accB ----------
__global__ void __launch_bounds__(256)
transform_l2(const float* __restrict__ accA, const unsigned short* __restrict__ Wb2,
             const float* __restrict__ b2, unsigned short* __restrict__ Y,
             float* __restrict__ accB, int N)
{
  const int lane = threadIdx.x & 63;
  const int wave = threadIdx.x >> 6;
  const int t = blockIdx.x * 4 + wave;
  if (t < ((N + 15) >> 4))
    transform_tile(t, N, lane, accA, 1, Wb2, b2, Y, accB);
}

// ---------- exclusive scan of cnt[n2] -> eptr8[n2] (+eptr8[n2]=E) ----------
#define SCAN_T 256
#define SCAN_E 4   // 1024 elems per block

__global__ void scan1(const int* __restrict__ cnt, int* __restrict__ bsum, int n) {
  __shared__ int lds[SCAN_T];
  int base = blockIdx.x * (SCAN_T * SCAN_E);
  int tid = threadIdx.x;
  int s = 0;
#pragma unroll
  for (int j = 0; j < SCAN_E; ++j) {
    int i = base + tid * SCAN_E + j;
    if (i < n) s += cnt[i];
  }
  lds[tid] = s; __syncthreads();
  for (int off = SCAN_T / 2; off > 0; off >>= 1) {
    if (tid < off) lds[tid] += lds[tid + off];
    __syncthreads();
  }
  if (tid == 0) bsum[blockIdx.x] = lds[0];
}

__global__ void scan2(int* __restrict__ bsum, int* __restrict__ eptr, int nb, int n) {
  __shared__ int lds[SCAN_T];
  int tid = threadIdx.x;
  int loc[4]; int s = 0;
#pragma unroll
  for (int j = 0; j < 4; ++j) {
    int i = tid * 4 + j;
    loc[j] = (i < nb) ? bsum[i] : 0; s += loc[j];
  }
  lds[tid] = s; __syncthreads();
  for (int off = 1; off < SCAN_T; off <<= 1) {   // Hillis-Steele inclusive
    int v = (tid >= off) ? lds[tid - off] : 0;
    __syncthreads();
    lds[tid] += v;
    __syncthreads();
  }
  int run = (tid > 0 ? lds[tid - 1] : 0);
#pragma unroll
  for (int j = 0; j < 4; ++j) {
    int i = tid * 4 + j;
    if (i < nb) { int v = loc[j]; bsum[i] = run; run += v; }
  }
  if (tid == 0) eptr[n] = lds[SCAN_T - 1];   // total = E
}

__global__ void scan3(const int* __restrict__ cnt, const int* __restrict__ bsum,
                      int* __restrict__ eptr, int n) {
  __shared__ int lds[SCAN_T];
  int base = blockIdx.x * (SCAN_T * SCAN_E);
  int tid = threadIdx.x;
  int loc[SCAN_E]; int s = 0;
#pragma unroll
  for (int j = 0; j < SCAN_E; ++j) {
    int i = base + tid * SCAN_E + j;
    loc[j] = (i < n) ? cnt[i] : 0; s += loc[j];
  }
  lds[tid] = s; __syncthreads();
  for (int off = 1; off < SCAN_T; off <<= 1) {
    int v = (tid >= off) ? lds[tid - off] : 0;
    __syncthreads();
    lds[tid] += v;
    __syncthreads();
  }
  int run = (tid > 0 ? lds[tid - 1] : 0) + bsum[blockIdx.x];
#pragma unroll
  for (int j = 0; j < SCAN_E; ++j) {
    int i = base + tid * SCAN_E + j;
    if (i < n) { eptr[i] = run; run += loc[j]; }
  }
}

// ---- CSR pass 2: deterministic placement, NO atomics. entry = (src<<3)|rel ----
__global__ void scatter_edges(const int* __restrict__ src, const int* __restrict__ dst,
                              const int* __restrict__ et, const int* __restrict__ eptr8,
                              const unsigned short* __restrict__ rank,
                              unsigned* __restrict__ entry, int E) {
  int e = blockIdx.x * blockDim.x + threadIdx.x;
  if (e < E) {
    int d = dst[e], r = et[e];
    int p = eptr8[d * 8 + r] + (int)rank[e];
    entry[p] = ((unsigned)src[e] << 3) | (unsigned)r;
  }
}

// ---------- CSR edge aggregation: one wave per dst node, no atomics.
// acc[d][lane] += sum_e Y[src_e][rel_e*64+lane] / cnt(d,rel_e).
// Paired-dword gather: lanes 0-31 carry the EVEN edge of each pair (features
// 2*sub, 2*sub+1 as one dword), lanes 32-63 the ODD edge -> one load
// instruction covers TWO edge rows => 16 edges in flight at vmcnt depth 8.
// Edge records prefetched 64-at-a-time (coalesced) + __shfl broadcast.
// Final 4-shfl repack restores feature-per-lane before the acc write.
__global__ void __launch_bounds__(256)
edge_agg_csr(const unsigned short* __restrict__ Y, const int* __restrict__ eptr8,
             const unsigned* __restrict__ entry, float* __restrict__ acc, int N)
{
  const int wid  = (blockIdx.x * blockDim.x + threadIdx.x) >> 6;
  const int lane = threadIdx.x & 63;
  if (wid >= N) return;
  const int bv = eptr8[wid * 8 + (lane < 9 ? lane : 8)];
  const int lo = __shfl(bv, 0), hi = __shfl(bv, 8);
  const int wdt = __shfl(bv, (lane & 7) + 1) - __shfl(bv, lane & 7);
  const float invv = 1.0f / (float)max(wdt, 1);   // lane r (0..7): 1/cnt(rel r)

  const int half = lane >> 5;      // 0 = even-edge stream, 1 = odd-edge stream
  const int sub  = lane & 31;      // feature pair: features 2*sub, 2*sub+1
  float s0 = 0.f, s1 = 0.f;

#define GATHER2(ename, vname, wname, pidx)                                     \
  unsigned ename = __shfl(en, 2 * (pidx) + half);                              \
  unsigned vname = *(const unsigned*)&Y[(size_t)(ename >> 3) * 512 +           \
                                        (ename & 7) * 64 + sub * 2];           \
  float wname = __shfl(invv, (int)(ename & 7));

  for (int base = lo; base < hi; base += 64) {
    const int rem = hi - base;
    const int mm = rem < 64 ? rem : 64;
    const unsigned en = entry[base + (lane < mm ? lane : mm - 1)];
    const int pairs = mm >> 1;
    int i = 0;
    for (; i + 8 <= pairs; i += 8) {
      GATHER2(ea, va, wa, i)     GATHER2(eb, vb, wb, i + 1)
      GATHER2(ec, vc, wc, i + 2) GATHER2(ed, vd, wd, i + 3)
      GATHER2(ee, ve, we, i + 4) GATHER2(ef, vf, wf, i + 5)
      GATHER2(eg, vg, wg, i + 6) GATHER2(eh, vh, wh, i + 7)
      s0 += bf2f((unsigned short)(va & 0xffff)) * wa + bf2f((unsigned short)(vb & 0xffff)) * wb
          + bf2f((unsigned short)(vc & 0xffff)) * wc + bf2f((unsigned short)(vd & 0xffff)) * wd
          + bf2f((unsigned short)(ve & 0xffff)) * we + bf2f((unsigned short)(vf & 0xffff)) * wf
          + bf2f((unsigned short)(vg & 0xffff)) * wg + bf2f((unsigned short)(vh & 0xffff)) * wh;
      s1 += bf2f((unsigned short)(va >> 16)) * wa + bf2f((unsigned short)(vb >> 16)) * wb
          + bf2f((unsigned short)(vc >> 16)) * wc + bf2f((unsigned short)(vd >> 16)) * wd
          + bf2f((unsigned short)(ve >> 16)) * we + bf2f((unsigned short)(vf >> 16)) * wf
          + bf2f((unsigned short)(vg >> 16)) * wg + bf2f((unsigned short)(vh >> 16)) * wh;
    }
    for (; i < pairs; ++i) {
      GATHER2(ea, va, wa, i)
      s0 += bf2f((unsigned short)(va & 0xffff)) * wa;
      s1 += bf2f((unsigned short)(va >> 16)) * wa;
    }
    if (mm & 1) {   // leftover odd edge -> even-stream lanes only
      unsigned e0 = __shfl(en, mm - 1);
      float w0 = __shfl(invv, (int)(e0 & 7));
      if (lane < 32) {
        unsigned v = *(const unsigned*)&Y[(size_t)(e0 >> 3) * 512 + (e0 & 7) * 64 + sub * 2];
        s0 += bf2f((unsigned short)(v & 0xffff)) * w0;
        s1 += bf2f((unsigned short)(v >> 16)) * w0;
      }
    }
  }
#undef GATHER2
  // repack: feature f = even-stream[lane f>>1, comp f&1] + odd-stream[lane 32+(f>>1), comp f&1]
  float a0 = __shfl(s0, lane >> 1);
  float a1 = __shfl(s1, lane >> 1);
  float b0 = __shfl(s0, 32 + (lane >> 1));
  float b1 = __shfl(s1, 32 + (lane >> 1));
  float sum = ((lane & 1) ? a1 : a0) + ((lane & 1) ? b1 : b0);
  acc[(size_t)wid * 64 + lane] += sum;
}

// lower_bound over sorted batch
__device__ inline int lbound(const int* __restrict__ batch, int Nn, int g) {
  int lo = 0, hi = Nn;
  while (lo < hi) { int m = (lo + hi) >> 1; if (batch[m] < g) lo = m + 1; else hi = m; }
  return lo;
}

// ---------- mean pool, two-stage (bounds via inline binary search) ----------
#define PS 24
__global__ void __launch_bounds__(256)
pool1(const float* __restrict__ acc, const int* __restrict__ batch,
      float* __restrict__ partial, int N, int G)
{
  const int g = blockIdx.x;
  const int s = blockIdx.y;
  const int lane = threadIdx.x & 63;
  const int w = threadIdx.x >> 6;
  const int lo = lbound(batch, N, g);
  const int hi = lbound(batch, N, g + 1);
  const int len = hi - lo;
  const int a = lo + (int)(((long long)len * s) / PS);
  const int b = lo + (int)(((long long)len * (s + 1)) / PS);
  float sum = 0.f;
  for (int n = a + w; n < b; n += 4) sum += acc[(size_t)n * 64 + lane];
  __shared__ float red[4][64];
  red[w][lane] = sum;
  __syncthreads();
  if (w == 0)
    partial[((size_t)g * PS + s) * 64 + lane] =
        red[0][lane] + red[1][lane] + red[2][lane] + red[3][lane];
}

__global__ void pool2(const float* __restrict__ partial, const int* __restrict__ batch,
                      float* __restrict__ out, int N, int G)
{
  const int g = blockIdx.x;
  const int lane = threadIdx.x;   // 64 threads
  float t = 0.f;
#pragma unroll
  for (int s = 0; s < PS; ++s) t += partial[((size_t)g * PS + s) * 64 + lane];
  const int len = lbound(batch, N, g + 1) - lbound(batch, N, g);
  out[(size_t)g * 64 + lane] = t / fmaxf((float)len, 1.0f);
}

// ---------- launch ----------
extern "C" void kernel_launch(void* const* d_in, const int* in_sizes, int n_in,
                              void* d_out, int out_size, void* d_ws, size_t ws_size,
                              hipStream_t stream)
{
  const float* x     = (const float*)d_in[0];
  const int*   ei    = (const int*)d_in[1];
  const int*   etype = (const int*)d_in[2];
  const int*   batch = (const int*)d_in[3];
  const float* W1    = (const float*)d_in[4];
  const float* root1 = (const float*)d_in[5];
  const float* b1    = (const float*)d_in[6];
  const float* W2    = (const float*)d_in[7];
  const float* root2 = (const float*)d_in[8];
  const float* b2    = (const float*)d_in[9];

  const int N = in_sizes[0] / 64;
  const int E = in_sizes[1] / 2;
  const int R = in_sizes[4] / (64 * 64);   // == 8
  const int G = out_size / 64;
  const int* srcp = ei;
  const int* dstp = ei + E;
  const int n2 = N * R;   // (dst,rel) bins

  // workspace carve-up (256B aligned), ~164 MB
  char* ws = (char*)d_ws;
  size_t off = 0;
  auto carve = [&](size_t bytes) -> void* {
    void* p = ws + off; off = (off + bytes + 255) & ~(size_t)255; return p;
  };
  float*          accA    = (float*)carve((size_t)N * 64 * 4);
  float*          accB    = (float*)carve((size_t)N * 64 * 4);
  unsigned short* Y       = (unsigned short*)carve((size_t)N * R * 64 * 2);
  int*            eptr8   = (int*)carve((size_t)(n2 + 1) * 4);
  unsigned*       entry   = (unsigned*)carve((size_t)E * 4);
  int*            bsum    = (int*)carve(1024 * 4);
  float*          partial = (float*)carve((size_t)G * PS * 64 * 4);
  unsigned short* Wb      = (unsigned short*)carve((size_t)2 * 9 * 4096 * 2);
  // dead-before-first-write aliases into accB (first written by transform_l2,
  // which runs AFTER scan3(cnt) and scatter(rank); same stream => ordered).
  // NOTE: must NOT alias accA — it is written concurrently by the fused kernel.
  int*            cnt  = (int*)accB;                               // 3.2 MB
  unsigned short* rank = (unsigned short*)((char*)accB + ((size_t)4 << 20));
  (void)ws_size; (void)n_in;

  const int nb2 = (n2 + SCAN_T * SCAN_E - 1) / (SCAN_T * SCAN_E);
  const int tiles = (N + 15) >> 4;
  const int TB = (tiles + 3) / 4;            // transform blocks (wave per tile)
  const int CB = (E + 255) / 256;            // count blocks (1 edge/thread)
  const int prep_total = 2 * 9 * 4096 + n2;

  // ---- prep: weights -> swizzled bf16, zero cnt ----
  conv_prep<<<(prep_total + 255) / 256, 256, 0, stream>>>(W1, root1, W2, root2, Wb, cnt, n2);

  // ---- FUSED: CSR count (atomic-bound) || layer-1 transform (MFMA/write-bound) ----
  count_and_t1<<<CB + TB, 256, 0, stream>>>(dstp, etype, cnt, rank, E,
                                            x, Wb, b1, Y, accA, N, TB);

  // ---- CSR finish ----
  scan1<<<nb2, SCAN_T, 0, stream>>>(cnt, bsum, n2);
  scan2<<<1, SCAN_T, 0, stream>>>(bsum, eptr8, nb2, n2);
  scan3<<<nb2, SCAN_T, 0, stream>>>(cnt, bsum, eptr8, n2);
  scatter_edges<<<(E + 255) / 256, 256, 0, stream>>>(srcp, dstp, etype, eptr8, rank, entry, E);

  const int aggBlocks = (N * 64 + 255) / 256;

  // ---- layer 1 aggregate ----
  edge_agg_csr<<<aggBlocks, 256, 0, stream>>>(Y, eptr8, entry, accA, N);

  // ---- layer 2 ----
  transform_l2<<<TB, 256, 0, stream>>>(accA, Wb + 9 * 4096, b2, Y, accB, N);
  edge_agg_csr<<<aggBlocks, 256, 0, stream>>>(Y, eptr8, entry, accB, N);

  // ---- global mean pool ----
  dim3 pgrid(G, PS);
  pool1<<<pgrid, 256, 0, stream>>>(accB, batch, partial, N, G);
  pool2<<<G, 64, 0, stream>>>(partial, batch, (float*)d_out, N, G);
}